// Round 17
// baseline (311.711 us; speedup 1.0000x reference)
//
#include <hip/hip_runtime.h>

#define TS 500      // n_patch (sequence length)
#define NB 16       // batch
#define NROW 8000   // NB * TS
#define DMODEL 256
#define NHEAD 8
#define HDIM 32
#define FFD 1024

typedef __bf16 bf16x8 __attribute__((ext_vector_type(8)));
typedef __bf16 bf16x4 __attribute__((ext_vector_type(4)));
typedef float  f32x4  __attribute__((ext_vector_type(4)));
typedef float  f32x2  __attribute__((ext_vector_type(2)));

__device__ __forceinline__ float wred_sum(float v) {
    #pragma unroll
    for (int off = 32; off; off >>= 1) v += __shfl_xor(v, off, 64);
    return v;
}

// A-fragment scatter store (global): element (grow, col) of [8000][K] bf16.
__device__ __forceinline__ void pa_store(__bf16* __restrict__ PA, int KS,
                                         int grow, int col, float y) {
    int mt = grow >> 4, rl = grow & 15;
    size_t idx = ((size_t)(mt * KS + (col >> 5)) * 64 + ((col >> 3) & 3) * 16 + rl) * 8 + (col & 7);
    PA[idx] = (__bf16)y;
}

// A-fragment scatter store (LDS, local row 0..31, KS=8)
__device__ __forceinline__ void ya_store(__bf16* __restrict__ YA,
                                         int lrow, int col, float y) {
    int mtl = lrow >> 4, rl = lrow & 15;
    int idx = (((mtl * 8 + (col >> 5)) * 64) + ((col >> 3) & 3) * 16 + rl) * 8 + (col & 7);
    YA[idx] = (__bf16)y;
}

// ---------------------------------------------------------------------------
// All weight packs in ONE kernel (unchanged, passing).
// ---------------------------------------------------------------------------
__global__ __launch_bounds__(256) void k_pack_all(
    const float* __restrict__ qkv_w, const float* __restrict__ out_w,
    const float* __restrict__ ff1_w, const float* __restrict__ ff2_w,
    const float* __restrict__ proj_w, const float* __restrict__ op_w,
    __bf16* __restrict__ PBq, __bf16* __restrict__ PBo,
    __bf16* __restrict__ PB1, __bf16* __restrict__ PB2,
    __bf16* __restrict__ PBp, __bf16* __restrict__ PBop)
{
    int bid = blockIdx.x;
    const float* W; __bf16* PB; int KS, NT, wLS, pLS, l, bx;
    if (bid < 384)       { W = qkv_w;  PB = PBq;  KS = 8;  NT = 48; wLS = 196608; pLS = 196608; l = bid / 96;           bx = bid % 96; }
    else if (bid < 512)  { W = out_w;  PB = PBo;  KS = 8;  NT = 16; wLS = 65536;  pLS = 65536;  l = (bid - 384) / 32;   bx = (bid - 384) % 32; }
    else if (bid < 1024) { W = ff1_w;  PB = PB1;  KS = 8;  NT = 64; wLS = 262144; pLS = 262144; l = (bid - 512) / 128;  bx = (bid - 512) % 128; }
    else if (bid < 1536) { W = ff2_w;  PB = PB2;  KS = 32; NT = 16; wLS = 262144; pLS = 262144; l = (bid - 1024) / 128; bx = (bid - 1024) % 128; }
    else if (bid < 1600) { W = proj_w; PB = PBp;  KS = 16; NT = 16; wLS = 0;      pLS = 0;      l = 0;                  bx = bid - 1536; }
    else                 { W = op_w;   PB = PBop; KS = 8;  NT = 8;  wLS = 0;      pLS = 0;      l = 0;                  bx = bid - 1600; }

    int gid = bx * 256 + threadIdx.x;
    if (gid >= NT * KS * 64) return;
    int lane = gid & 63;
    int ks = (gid >> 6) % KS;
    int nt = (gid >> 6) / KS;
    int N = NT * 16;
    int k0 = ks * 32 + (lane >> 4) * 8;
    int col = nt * 16 + (lane & 15);
    const float* src = W + (size_t)l * wLS;
    bf16x8 v;
    #pragma unroll
    for (int j = 0; j < 8; j++) v[j] = (__bf16)src[(size_t)(k0 + j) * N + col];
    *(bf16x8*)(PB + (size_t)l * pLS + ((size_t)(nt * KS + ks) * 64 + lane) * 8) = v;
}

// ---------------------------------------------------------------------------
// Patch stage FUSED + qkv[0] (unchanged, passing).
// ---------------------------------------------------------------------------
__global__ __launch_bounds__(256) void k_patchfused(
    const float* __restrict__ x, const float* __restrict__ g1, const float* __restrict__ b1,
    const __bf16* __restrict__ PBp, const float* __restrict__ bias,
    float* __restrict__ h,
    const float* __restrict__ gam, const float* __restrict__ bet,
    const float* __restrict__ gam2, const float* __restrict__ bet2,
    const __bf16* __restrict__ PBq0, const float* __restrict__ qb0,
    __bf16* __restrict__ qkvb)
{
    __shared__ __align__(16) __bf16 As[2][16][64][8];
    __shared__ float redS[4][32];
    __shared__ float redQ[4][32];
    int t = threadIdx.x, lane = t & 63, w = t >> 6;
    int row0 = blockIdx.x * 32;

    for (int rr = 0; rr < 8; rr++) {
        int lrow = w * 8 + rr;
        int row = row0 + lrow;
        int b = row / TS, pp = row - b * TS;
        int kb = lane * 8;
        const float* src = x + ((size_t)(pp * 4 + (kb >> 7)) * NB + b) * 128 + (kb & 127);
        float4 lo = *(const float4*)src;
        float4 hi = *(const float4*)(src + 4);
        float v[8] = {lo.x, lo.y, lo.z, lo.w, hi.x, hi.y, hi.z, hi.w};
        float sm_ = 0.f;
        #pragma unroll
        for (int j = 0; j < 8; j++) sm_ += v[j];
        sm_ = wred_sum(sm_);
        float mu = sm_ * (1.0f / 512.0f);
        float q = 0.f;
        #pragma unroll
        for (int j = 0; j < 8; j++) { float d = v[j] - mu; q += d * d; }
        q = wred_sum(q);
        float rs = rsqrtf(q * (1.0f / 512.0f) + 1e-6f);
        float4 gl = *(const float4*)(g1 + kb), gh = *(const float4*)(g1 + kb + 4);
        float4 bl = *(const float4*)(b1 + kb), bh = *(const float4*)(b1 + kb + 4);
        float gg[8] = {gl.x, gl.y, gl.z, gl.w, gh.x, gh.y, gh.z, gh.w};
        float bbv[8] = {bl.x, bl.y, bl.z, bl.w, bh.x, bh.y, bh.z, bh.w};
        bf16x8 yv;
        #pragma unroll
        for (int j = 0; j < 8; j++) yv[j] = (__bf16)((v[j] - mu) * rs * gg[j] + bbv[j]);
        *(bf16x8*)&As[lrow >> 4][lane >> 2][(lane & 3) * 16 + (lrow & 15)][0] = yv;
    }
    __syncthreads();

    const bf16x8* B8 = (const bf16x8*)PBp;
    f32x4 acc[2][4] = {};
    #pragma unroll 8
    for (int ks = 0; ks < 16; ks++) {
        bf16x8 a0 = *(const bf16x8*)&As[0][ks][lane][0];
        bf16x8 a1 = *(const bf16x8*)&As[1][ks][lane][0];
        #pragma unroll
        for (int n = 0; n < 4; n++) {
            bf16x8 b = B8[((size_t)(w * 4 + n) * 16 + ks) * 64 + lane];
            acc[0][n] = __builtin_amdgcn_mfma_f32_16x16x32_bf16(a0, b, acc[0][n], 0, 0, 0);
            acc[1][n] = __builtin_amdgcn_mfma_f32_16x16x32_bf16(a1, b, acc[1][n], 0, 0, 0);
        }
    }

    int g_ = lane >> 4, cl = lane & 15;
    int rbase = g_ * 4;
    float gamv[4], betv[4], gam2v[4], bet2v[4];
    #pragma unroll
    for (int n = 0; n < 4; n++) {
        int col = (w * 4 + n) * 16 + cl;
        float bv = bias[col];
        gamv[n] = gam[col]; betv[n] = bet[col];
        gam2v[n] = gam2[col]; bet2v[n] = bet2[col];
        #pragma unroll
        for (int m = 0; m < 2; m++)
            #pragma unroll
            for (int r = 0; r < 4; r++) acc[m][n][r] += bv;
    }
    float mu[2][4], rstd[2][4];
    {
        float ps[2][4];
        #pragma unroll
        for (int m = 0; m < 2; m++)
            #pragma unroll
            for (int r = 0; r < 4; r++) {
                float s2 = acc[m][0][r] + acc[m][1][r] + acc[m][2][r] + acc[m][3][r];
                #pragma unroll
                for (int off = 1; off < 16; off <<= 1) s2 += __shfl_xor(s2, off, 64);
                ps[m][r] = s2;
            }
        if (cl == 0)
            #pragma unroll
            for (int m = 0; m < 2; m++)
                #pragma unroll
                for (int r = 0; r < 4; r++) redS[w][m * 16 + rbase + r] = ps[m][r];
        __syncthreads();
        #pragma unroll
        for (int m = 0; m < 2; m++)
            #pragma unroll
            for (int r = 0; r < 4; r++) {
                int lr = m * 16 + rbase + r;
                mu[m][r] = (redS[0][lr] + redS[1][lr] + redS[2][lr] + redS[3][lr]) * (1.0f / 256.0f);
            }
        float pq[2][4];
        #pragma unroll
        for (int m = 0; m < 2; m++)
            #pragma unroll
            for (int r = 0; r < 4; r++) {
                float s2 = 0.f;
                #pragma unroll
                for (int n = 0; n < 4; n++) { float d = acc[m][n][r] - mu[m][r]; s2 += d * d; }
                #pragma unroll
                for (int off = 1; off < 16; off <<= 1) s2 += __shfl_xor(s2, off, 64);
                pq[m][r] = s2;
            }
        if (cl == 0)
            #pragma unroll
            for (int m = 0; m < 2; m++)
                #pragma unroll
                for (int r = 0; r < 4; r++) redQ[w][m * 16 + rbase + r] = pq[m][r];
        __syncthreads();
        #pragma unroll
        for (int m = 0; m < 2; m++)
            #pragma unroll
            for (int r = 0; r < 4; r++) {
                int lr = m * 16 + rbase + r;
                float var = (redQ[0][lr] + redQ[1][lr] + redQ[2][lr] + redQ[3][lr]) * (1.0f / 256.0f);
                rstd[m][r] = rsqrtf(var + 1e-6f);
            }
    }
    float ps2[2][4];
    #pragma unroll
    for (int m = 0; m < 2; m++) {
        int row = row0 + m * 16 + rbase;
        #pragma unroll
        for (int r = 0; r < 4; r++) {
            float s2 = 0.f;
            #pragma unroll
            for (int n = 0; n < 4; n++) {
                int col = (w * 4 + n) * 16 + cl;
                float y1 = (acc[m][n][r] - mu[m][r]) * rstd[m][r] * gamv[n] + betv[n];
                h[(size_t)(row + r) * 256 + col] = y1;
                s2 += y1;
            }
            #pragma unroll
            for (int off = 1; off < 16; off <<= 1) s2 += __shfl_xor(s2, off, 64);
            ps2[m][r] = s2;
        }
    }
    if (cl == 0)
        #pragma unroll
        for (int m = 0; m < 2; m++)
            #pragma unroll
            for (int r = 0; r < 4; r++) redS[w][m * 16 + rbase + r] = ps2[m][r];
    __syncthreads();
    float mu2[2][4], rstd2[2][4];
    #pragma unroll
    for (int m = 0; m < 2; m++)
        #pragma unroll
        for (int r = 0; r < 4; r++) {
            int lr = m * 16 + rbase + r;
            mu2[m][r] = (redS[0][lr] + redS[1][lr] + redS[2][lr] + redS[3][lr]) * (1.0f / 256.0f);
        }
    float pq2[2][4];
    #pragma unroll
    for (int m = 0; m < 2; m++)
        #pragma unroll
        for (int r = 0; r < 4; r++) {
            float s2 = 0.f;
            #pragma unroll
            for (int n = 0; n < 4; n++) {
                float y1 = (acc[m][n][r] - mu[m][r]) * rstd[m][r] * gamv[n] + betv[n];
                float d = y1 - mu2[m][r];
                s2 += d * d;
            }
            #pragma unroll
            for (int off = 1; off < 16; off <<= 1) s2 += __shfl_xor(s2, off, 64);
            pq2[m][r] = s2;
        }
    if (cl == 0)
        #pragma unroll
        for (int m = 0; m < 2; m++)
            #pragma unroll
            for (int r = 0; r < 4; r++) redQ[w][m * 16 + rbase + r] = pq2[m][r];
    __syncthreads();
    #pragma unroll
    for (int m = 0; m < 2; m++)
        #pragma unroll
        for (int r = 0; r < 4; r++) {
            int lr = m * 16 + rbase + r;
            float var = (redQ[0][lr] + redQ[1][lr] + redQ[2][lr] + redQ[3][lr]) * (1.0f / 256.0f);
            rstd2[m][r] = rsqrtf(var + 1e-5f);
        }
    __bf16* YA = &As[0][0][0][0];
    #pragma unroll
    for (int m = 0; m < 2; m++) {
        #pragma unroll
        for (int n = 0; n < 4; n++) {
            int col = (w * 4 + n) * 16 + cl;
            #pragma unroll
            for (int r = 0; r < 4; r++) {
                float y1 = (acc[m][n][r] - mu[m][r]) * rstd[m][r] * gamv[n] + betv[n];
                float y2 = (y1 - mu2[m][r]) * rstd2[m][r] * gam2v[n] + bet2v[n];
                ya_store(YA, m * 16 + rbase + r, col, y2);
            }
        }
    }
    __syncthreads();

    const bf16x8* YA8 = (const bf16x8*)YA;
    const bf16x8* B8q = (const bf16x8*)PBq0;
    for (int m = 0; m < 2; m++) {
        f32x4 acc2[12] = {};
        for (int ks = 0; ks < 8; ks++) {
            bf16x8 a = YA8[(m * 8 + ks) * 64 + lane];
            #pragma unroll
            for (int n = 0; n < 12; n++) {
                bf16x8 b = B8q[((size_t)(w * 12 + n) * 8 + ks) * 64 + lane];
                acc2[n] = __builtin_amdgcn_mfma_f32_16x16x32_bf16(a, b, acc2[n], 0, 0, 0);
            }
        }
        int row = row0 + m * 16 + rbase;
        #pragma unroll
        for (int n = 0; n < 12; n++) {
            int col = (w * 12 + n) * 16 + cl;
            float bv = qb0[col];
            #pragma unroll
            for (int r = 0; r < 4; r++)
                qkvb[(size_t)(row + r) * 768 + col] = (__bf16)(acc2[n][r] + bv);
        }
    }
}

// ---------------------------------------------------------------------------
// FULL LAYER TAIL, MT=2 (32 rows/block, grid 250): out-proj + residual (h in
// regs) + LN_ff -> YA; ff1+GELU+ff2 in TWO K-halves (F1T planes per m-tile);
// residual -> h (single write) + LN -> YA -> tail GEMM (MODE 0: qkv[l+1];
// MODE 1: final projection, swapaxes). 512 threads / 8 waves. LDS ~50 KB.
// ---------------------------------------------------------------------------
template<int MODE>
__global__ __launch_bounds__(512) void k_layer(
    const __bf16* __restrict__ PAattn, const __bf16* __restrict__ PBo,
    const float* __restrict__ ob, float* __restrict__ h,
    const float* __restrict__ fg, const float* __restrict__ fb,
    const __bf16* __restrict__ PB1, const float* __restrict__ b1,
    const __bf16* __restrict__ PB2, const float* __restrict__ b2,
    const float* __restrict__ gam, const float* __restrict__ bet,
    const __bf16* __restrict__ PBn, const float* __restrict__ bn,
    __bf16* __restrict__ qkvb, float* __restrict__ outp)
{
    __shared__ __align__(16) __bf16 YA[2 * 8 * 64 * 8];   // 16 KB (32 rows)
    __shared__ __align__(16) __bf16 F1T[2][512][16];      // 32 KB, plane per m
    __shared__ float redS[8][32];
    __shared__ float redQ[8][32];
    int t = threadIdx.x, lane = t & 63, w = t >> 6;  // w in 0..7
    int mt0 = blockIdx.x * 2;
    int g_ = lane >> 4, cl = lane & 15, rbase = g_ * 4;

    const bf16x8* A8 = (const bf16x8*)PAattn;
    const bf16x8* B8o = (const bf16x8*)PBo;
    const bf16x8* B81 = (const bf16x8*)PB1;
    const bf16x8* B82 = (const bf16x8*)PB2;

    // ---- Phase 0: out-projection GEMM (K=256), both m-tiles, 2 n-tiles/wave
    f32x4 hv[2][2];
    {
        f32x4 acc0[2][2] = {};
        #pragma unroll 8
        for (int ks = 0; ks < 8; ks++) {
            bf16x8 a0 = A8[((size_t)mt0 * 8 + ks) * 64 + lane];
            bf16x8 a1 = A8[((size_t)(mt0 + 1) * 8 + ks) * 64 + lane];
            #pragma unroll
            for (int n = 0; n < 2; n++) {
                bf16x8 b = B8o[((size_t)(w * 2 + n) * 8 + ks) * 64 + lane];
                acc0[0][n] = __builtin_amdgcn_mfma_f32_16x16x32_bf16(a0, b, acc0[0][n], 0, 0, 0);
                acc0[1][n] = __builtin_amdgcn_mfma_f32_16x16x32_bf16(a1, b, acc0[1][n], 0, 0, 0);
            }
        }
        #pragma unroll
        for (int n = 0; n < 2; n++) {
            int col = (w * 2 + n) * 16 + cl;
            float bv = ob[col];
            #pragma unroll
            for (int m = 0; m < 2; m++) {
                int row = (mt0 + m) * 16 + rbase;
                #pragma unroll
                for (int r = 0; r < 4; r++)
                    hv[m][n][r] = acc0[m][n][r] + bv + h[(size_t)(row + r) * 256 + col];
            }
        }
    }
    // ---- LN_ff(hv) -> YA ----
    {
        float mu[2][4], rstd[2][4];
        float ps[2][4];
        #pragma unroll
        for (int m = 0; m < 2; m++)
            #pragma unroll
            for (int r = 0; r < 4; r++) {
                float s2 = hv[m][0][r] + hv[m][1][r];
                #pragma unroll
                for (int off = 1; off < 16; off <<= 1) s2 += __shfl_xor(s2, off, 64);
                ps[m][r] = s2;
            }
        if (cl == 0)
            #pragma unroll
            for (int m = 0; m < 2; m++)
                #pragma unroll
                for (int r = 0; r < 4; r++) redS[w][m * 16 + rbase + r] = ps[m][r];
        __syncthreads();
        #pragma unroll
        for (int m = 0; m < 2; m++)
            #pragma unroll
            for (int r = 0; r < 4; r++) {
                int lr = m * 16 + rbase + r;
                float s2 = 0.f;
                #pragma unroll
                for (int ww = 0; ww < 8; ww++) s2 += redS[ww][lr];
                mu[m][r] = s2 * (1.0f / 256.0f);
            }
        float pq[2][4];
        #pragma unroll
        for (int m = 0; m < 2; m++)
            #pragma unroll
            for (int r = 0; r < 4; r++) {
                float s2 = 0.f;
                #pragma unroll
                for (int n = 0; n < 2; n++) { float d = hv[m][n][r] - mu[m][r]; s2 += d * d; }
                #pragma unroll
                for (int off = 1; off < 16; off <<= 1) s2 += __shfl_xor(s2, off, 64);
                pq[m][r] = s2;
            }
        if (cl == 0)
            #pragma unroll
            for (int m = 0; m < 2; m++)
                #pragma unroll
                for (int r = 0; r < 4; r++) redQ[w][m * 16 + rbase + r] = pq[m][r];
        __syncthreads();
        #pragma unroll
        for (int m = 0; m < 2; m++)
            #pragma unroll
            for (int r = 0; r < 4; r++) {
                int lr = m * 16 + rbase + r;
                float s2 = 0.f;
                #pragma unroll
                for (int ww = 0; ww < 8; ww++) s2 += redQ[ww][lr];
                rstd[m][r] = rsqrtf(s2 * (1.0f / 256.0f) + 1e-5f);
            }
        #pragma unroll
        for (int n = 0; n < 2; n++) {
            int col = (w * 2 + n) * 16 + cl;
            float gv = fg[col], bv = fb[col];
            #pragma unroll
            for (int m = 0; m < 2; m++)
                #pragma unroll
                for (int r = 0; r < 4; r++) {
                    float y = (hv[m][n][r] - mu[m][r]) * rstd[m][r] * gv + bv;
                    ya_store(YA, m * 16 + rbase + r, col, y);
                }
        }
    }
    __syncthreads();

    // ---- ff1+ff2 in two K-halves ----
    const bf16x8* YA8 = (const bf16x8*)YA;
    f32x4 acc[2][2] = {};
    #pragma unroll
    for (int hf = 0; hf < 2; hf++) {
        // Phase A: ff1 cols [hf*512, hf*512+512), wave owns 4 n-tiles, both m
        {
            f32x4 acc1[2][4] = {};
            #pragma unroll 2
            for (int ks = 0; ks < 8; ks++) {
                bf16x8 a0 = YA8[ks * 64 + lane];
                bf16x8 a1 = YA8[(8 + ks) * 64 + lane];
                #pragma unroll
                for (int n = 0; n < 4; n++) {
                    int nt = hf * 32 + w * 4 + n;
                    bf16x8 b = B81[((size_t)nt * 8 + ks) * 64 + lane];
                    acc1[0][n] = __builtin_amdgcn_mfma_f32_16x16x32_bf16(a0, b, acc1[0][n], 0, 0, 0);
                    acc1[1][n] = __builtin_amdgcn_mfma_f32_16x16x32_bf16(a1, b, acc1[1][n], 0, 0, 0);
                }
            }
            #pragma unroll
            for (int n = 0; n < 4; n++) {
                int colh = (w * 4 + n) * 16 + cl;
                float bv = b1[hf * 512 + colh];
                #pragma unroll
                for (int m = 0; m < 2; m++) {
                    bf16x4 pv;
                    #pragma unroll
                    for (int r = 0; r < 4; r++) {
                        float xx = acc1[m][n][r] + bv;
                        pv[r] = (__bf16)(0.5f * xx * (1.0f + erff(xx * 0.70710678118654752f)));
                    }
                    *(bf16x4*)&F1T[m][colh][rbase] = pv;
                }
            }
        }
        __syncthreads();

        // Phase B: ff2 partial over 16 k-slices, wave owns 2 n-tiles, both m
        for (int kb = 0; kb < 4; kb++) {
            f32x2 lo[2][4], hi[2][4];
            #pragma unroll
            for (int q = 0; q < 4; q++) {
                #pragma unroll
                for (int m = 0; m < 2; m++) {
                    unsigned ta = (unsigned)(uintptr_t)&F1T[m][(kb * 4 + q) * 32 + 8 * g_][0] + cl * 8;
                    asm volatile("ds_read_b64_tr_b16 %0, %1" : "=v"(lo[m][q]) : "v"(ta) : "memory");
                    asm volatile("ds_read_b64_tr_b16 %0, %1 offset:128" : "=v"(hi[m][q]) : "v"(ta) : "memory");
                }
            }
            asm volatile("s_waitcnt lgkmcnt(0)" ::: "memory");
            __builtin_amdgcn_sched_barrier(0);
            #pragma unroll
            for (int q = 0; q < 4; q++) {
                int ks = hf * 16 + kb * 4 + q;
                bf16x8 a[2];
                #pragma unroll
                for (int m = 0; m < 2; m++) {
                    f32x4 pc = {lo[m][q][0], lo[m][q][1], hi[m][q][0], hi[m][q][1]};
                    a[m] = __builtin_bit_cast(bf16x8, pc);
                }
                #pragma unroll
                for (int n = 0; n < 2; n++) {
                    bf16x8 b = B82[((size_t)(w * 2 + n) * 32 + ks) * 64 + lane];
                    acc[0][n] = __builtin_amdgcn_mfma_f32_16x16x32_bf16(a[0], b, acc[0][n], 0, 0, 0);
                    acc[1][n] = __builtin_amdgcn_mfma_f32_16x16x32_bf16(a[1], b, acc[1][n], 0, 0, 0);
                }
            }
        }
        __syncthreads();
    }

    // ---- EPI: +b2, residual (hv), single h write, LN -> YA ----
    float gamv[2], betv[2];
    #pragma unroll
    for (int n = 0; n < 2; n++) {
        int col = (w * 2 + n) * 16 + cl;
        float bv = b2[col];
        gamv[n] = gam[col]; betv[n] = bet[col];
        #pragma unroll
        for (int m = 0; m < 2; m++) {
            int row = (mt0 + m) * 16 + rbase;
            #pragma unroll
            for (int r = 0; r < 4; r++) {
                float v = acc[m][n][r] + bv + hv[m][n][r];
                h[(size_t)(row + r) * 256 + col] = v;
                acc[m][n][r] = v;
            }
        }
    }
    {
        float mu[2][4], rstd[2][4];
        float ps[2][4];
        #pragma unroll
        for (int m = 0; m < 2; m++)
            #pragma unroll
            for (int r = 0; r < 4; r++) {
                float s2 = acc[m][0][r] + acc[m][1][r];
                #pragma unroll
                for (int off = 1; off < 16; off <<= 1) s2 += __shfl_xor(s2, off, 64);
                ps[m][r] = s2;
            }
        if (cl == 0)
            #pragma unroll
            for (int m = 0; m < 2; m++)
                #pragma unroll
                for (int r = 0; r < 4; r++) redS[w][m * 16 + rbase + r] = ps[m][r];
        __syncthreads();
        #pragma unroll
        for (int m = 0; m < 2; m++)
            #pragma unroll
            for (int r = 0; r < 4; r++) {
                int lr = m * 16 + rbase + r;
                float s2 = 0.f;
                #pragma unroll
                for (int ww = 0; ww < 8; ww++) s2 += redS[ww][lr];
                mu[m][r] = s2 * (1.0f / 256.0f);
            }
        float pq[2][4];
        #pragma unroll
        for (int m = 0; m < 2; m++)
            #pragma unroll
            for (int r = 0; r < 4; r++) {
                float s2 = 0.f;
                #pragma unroll
                for (int n = 0; n < 2; n++) { float d = acc[m][n][r] - mu[m][r]; s2 += d * d; }
                #pragma unroll
                for (int off = 1; off < 16; off <<= 1) s2 += __shfl_xor(s2, off, 64);
                pq[m][r] = s2;
            }
        if (cl == 0)
            #pragma unroll
            for (int m = 0; m < 2; m++)
                #pragma unroll
                for (int r = 0; r < 4; r++) redQ[w][m * 16 + rbase + r] = pq[m][r];
        __syncthreads();
        #pragma unroll
        for (int m = 0; m < 2; m++)
            #pragma unroll
            for (int r = 0; r < 4; r++) {
                int lr = m * 16 + rbase + r;
                float s2 = 0.f;
                #pragma unroll
                for (int ww = 0; ww < 8; ww++) s2 += redQ[ww][lr];
                rstd[m][r] = rsqrtf(s2 * (1.0f / 256.0f) + 1e-5f);
            }
        #pragma unroll
        for (int n = 0; n < 2; n++) {
            int col = (w * 2 + n) * 16 + cl;
            #pragma unroll
            for (int m = 0; m < 2; m++)
                #pragma unroll
                for (int r = 0; r < 4; r++) {
                    float y = (acc[m][n][r] - mu[m][r]) * rstd[m][r] * gamv[n] + betv[n];
                    ya_store(YA, m * 16 + rbase + r, col, y);
                }
        }
    }
    __syncthreads();

    // ---- tail GEMM from YA, both m-tiles per B load ----
    const bf16x8* B8n = (const bf16x8*)PBn;
    if constexpr (MODE == 0) {
        f32x4 acc2[2][6] = {};
        for (int ks = 0; ks < 8; ks++) {
            bf16x8 a0 = YA8[ks * 64 + lane];
            bf16x8 a1 = YA8[(8 + ks) * 64 + lane];
            #pragma unroll
            for (int n = 0; n < 6; n++) {
                bf16x8 b = B8n[((size_t)(w * 6 + n) * 8 + ks) * 64 + lane];
                acc2[0][n] = __builtin_amdgcn_mfma_f32_16x16x32_bf16(a0, b, acc2[0][n], 0, 0, 0);
                acc2[1][n] = __builtin_amdgcn_mfma_f32_16x16x32_bf16(a1, b, acc2[1][n], 0, 0, 0);
            }
        }
        #pragma unroll
        for (int n = 0; n < 6; n++) {
            int col = (w * 6 + n) * 16 + cl;
            float bv = bn[col];
            #pragma unroll
            for (int m = 0; m < 2; m++) {
                int row = (mt0 + m) * 16 + rbase;
                #pragma unroll
                for (int r = 0; r < 4; r++)
                    qkvb[(size_t)(row + r) * 768 + col] = (__bf16)(acc2[m][n][r] + bv);
            }
        }
    } else {
        f32x4 acc2[2] = {};
        #pragma unroll 4
        for (int ks = 0; ks < 8; ks++) {
            bf16x8 a0 = YA8[ks * 64 + lane];
            bf16x8 a1 = YA8[(8 + ks) * 64 + lane];
            bf16x8 b = B8n[((size_t)w * 8 + ks) * 64 + lane];
            acc2[0] = __builtin_amdgcn_mfma_f32_16x16x32_bf16(a0, b, acc2[0], 0, 0, 0);
            acc2[1] = __builtin_amdgcn_mfma_f32_16x16x32_bf16(a1, b, acc2[1], 0, 0, 0);
        }
        int col = w * 16 + cl;
        float bv = bn[col];
        #pragma unroll
        for (int m = 0; m < 2; m++) {
            int row = (mt0 + m) * 16 + rbase;
            #pragma unroll
            for (int r = 0; r < 4; r++) {
                int grow = row + r;
                int bq = grow / TS, pp = grow - bq * TS;
                outp[((size_t)pp * NB + bq) * 128 + col] = acc2[m][r] + bv;
            }
        }
    }
}

// ---------------------------------------------------------------------------
// MFMA flash attention, qt-PAIRED (unchanged, passing).
// ---------------------------------------------------------------------------
__global__ __launch_bounds__(512) void k_attn(
    const __bf16* __restrict__ qkv, const float* __restrict__ rel_bias,
    __bf16* __restrict__ PA)
{
    __shared__ __align__(16) __bf16 Kfr[4][64][8];
    __shared__ __align__(16) __bf16 Vpl[2][64][16];
    __shared__ __align__(16) __bf16 PT[8][64][16];
    __shared__ float bias_s[132];

    int bh = blockIdx.x;
    int pr = 3 - blockIdx.y;
    int b = bh >> 3, hh = bh & 7;
    int t = threadIdx.x, lane = t & 63, w = t >> 6;
    int wg = w & 3, grp = w >> 2;
    int qt = 2 * pr + 1 - grp;
    int q0 = qt * 64 + wg * 16;
    int c = lane & 15, g = lane >> 4;

    const __bf16* base = qkv + (size_t)b * TS * 768 + hh * 32;

    if (t < 129) bias_s[t] = rel_bias[hh * 129 + t];

    bf16x8 aq = {};
    {
        int qi = q0 + c;
        if (qi < TS) aq = *(const bf16x8*)(base + (size_t)qi * 768 + 8 * g);
    }

    float lpart[4] = {0.f, 0.f, 0.f, 0.f};
    f32x4 O0 = {}, O1 = {};
    const float scale = 0.17677669529663687f;

    int nj = 2 * pr + 2;

    for (int it = 0; it < nj; it++) {
        int j0 = it * 64;
        __syncthreads();
        if (w < 4) {
            int j = j0 + w * 16 + c;
            bf16x8 kv = {};
            if (j < TS) kv = *(const bf16x8*)(base + (size_t)j * 768 + 256 + 8 * g);
            *(bf16x8*)&Kfr[w][lane][0] = kv;
        } else {
            int t2 = t - 256;
            int jl = t2 >> 2, dseg = t2 & 3;
            int j = j0 + jl;
            bf16x8 vv = {};
            if (j < TS) vv = *(const bf16x8*)(base + (size_t)j * 768 + 512 + 8 * dseg);
            *(bf16x8*)&Vpl[dseg >> 1][jl][(dseg & 1) * 8] = vv;
        }
        __syncthreads();

        if (it > qt) continue;

        f32x4 S[4];
        f32x4 zero = {};
        #pragma unroll
        for (int jt = 0; jt < 4; jt++) {
            bf16x8 bk = *(const bf16x8*)&Kfr[jt][lane][0];
            S[jt] = __builtin_amdgcn_mfma_f32_16x16x32_bf16(aq, bk, zero, 0, 0, 0);
        }

        #pragma unroll
        for (int jt = 0; jt < 4; jt++) {
            int j = j0 + jt * 16 + c;
            #pragma unroll
            for (int r = 0; r < 4; r++) {
                int i = q0 + 4 * g + r;
                int rel = j - i;
                rel = rel < -64 ? -64 : (rel > 64 ? 64 : rel);
                float sv = S[jt][r] * scale + bias_s[rel + 64];
                float pr_ = (j > i) ? 0.f : __expf(sv);
                S[jt][r] = pr_;
                lpart[r] += pr_;
            }
        }

        #pragma unroll
        for (int jt = 0; jt < 4; jt++) {
            bf16x4 pv;
            pv[0] = (__bf16)S[jt][0]; pv[1] = (__bf16)S[jt][1];
            pv[2] = (__bf16)S[jt][2]; pv[3] = (__bf16)S[jt][3];
            *(bf16x4*)&PT[w][jt * 16 + c][4 * g] = pv;
        }
        asm volatile("s_waitcnt lgkmcnt(0)" ::: "memory");
        __builtin_amdgcn_sched_barrier(0);

        f32x2 pa_lo[2], pa_hi[2], vb_lo[2][2], vb_hi[2][2];
        #pragma unroll
        for (int jb = 0; jb < 2; jb++) {
            unsigned pta = (unsigned)(uintptr_t)&PT[w][jb * 32 + 8 * g][0] + c * 8;
            asm volatile("ds_read_b64_tr_b16 %0, %1" : "=v"(pa_lo[jb]) : "v"(pta) : "memory");
            asm volatile("ds_read_b64_tr_b16 %0, %1 offset:128" : "=v"(pa_hi[jb]) : "v"(pta) : "memory");
            #pragma unroll
            for (int dh = 0; dh < 2; dh++) {
                unsigned vta = (unsigned)(uintptr_t)&Vpl[dh][jb * 32 + 8 * g][0] + c * 8;
                asm volatile("ds_read_b64_tr_b16 %0, %1" : "=v"(vb_lo[jb][dh]) : "v"(vta) : "memory");
                asm volatile("ds_read_b64_tr_b16 %0, %1 offset:128" : "=v"(vb_hi[jb][dh]) : "v"(vta) : "memory");
            }
        }
        asm volatile("s_waitcnt lgkmcnt(0)" ::: "memory");
        __builtin_amdgcn_sched_barrier(0);

        #pragma unroll
        for (int jb = 0; jb < 2; jb++) {
            f32x4 pc = {pa_lo[jb][0], pa_lo[jb][1], pa_hi[jb][0], pa_hi[jb][1]};
            bf16x8 pa = __builtin_bit_cast(bf16x8, pc);
            f32x4 v0c = {vb_lo[jb][0][0], vb_lo[jb][0][1], vb_hi[jb][0][0], vb_hi[jb][0][1]};
            f32x4 v1c = {vb_lo[jb][1][0], vb_lo[jb][1][1], vb_hi[jb][1][0], vb_hi[jb][1][1]};
            bf16x8 vb0 = __builtin_bit_cast(bf16x8, v0c);
            bf16x8 vb1 = __builtin_bit_cast(bf16x8, v1c);
            O0 = __builtin_amdgcn_mfma_f32_16x16x32_bf16(pa, vb0, O0, 0, 0, 0);
            O1 = __builtin_amdgcn_mfma_f32_16x16x32_bf16(pa, vb1, O1, 0, 0, 0);
        }
    }

    #pragma unroll
    for (int r = 0; r < 4; r++) {
        #pragma unroll
        for (int off = 1; off < 16; off <<= 1) lpart[r] += __shfl_xor(lpart[r], off, 64);
    }
    #pragma unroll
    for (int r = 0; r < 4; r++) {
        int i = q0 + 4 * g + r;
        if (i < TS) {
            float inv = 1.0f / lpart[r];
            int grow = b * TS + i;
            int mt = grow >> 4, rl = grow & 15;
            size_t fb = (size_t)(mt * 8 + hh) * 64;
            PA[(fb + ((c >> 3) & 1) * 16 + rl) * 8 + (c & 7)]       = (__bf16)(O0[r] * inv);
            PA[(fb + (2 + ((c >> 3) & 1)) * 16 + rl) * 8 + (c & 7)] = (__bf16)(O1[r] * inv);
        }
    }
}

extern "C" void kernel_launch(void* const* d_in, const int* in_sizes, int n_in,
                              void* d_out, int out_size, void* d_ws, size_t ws_size,
                              hipStream_t stream)
{
    const float* x        = (const float*)d_in[0];
    const float* ln1_g    = (const float*)d_in[1];
    const float* ln1_b    = (const float*)d_in[2];
    const float* proj_w   = (const float*)d_in[3];
    const float* proj_b   = (const float*)d_in[4];
    const float* ln2_g    = (const float*)d_in[5];
    const float* ln2_b    = (const float*)d_in[6];
    const float* rel_bias = (const float*)d_in[7];
    const float* ln_attn_g= (const float*)d_in[8];
    const float* ln_attn_b= (const float*)d_in[9];
    const float* qkv_w    = (const float*)d_in[10];
    const float* qkv_b    = (const float*)d_in[11];
    const float* out_w    = (const float*)d_in[12];
    const float* out_b    = (const float*)d_in[13];
    const float* ln_ff_g  = (const float*)d_in[14];
    const float* ln_ff_b  = (const float*)d_in[15];
    const float* ff1_w    = (const float*)d_in[16];
    const float* ff1_b    = (const float*)d_in[17];
    const float* ff2_w    = (const float*)d_in[18];
    const float* ff2_b    = (const float*)d_in[19];
    const float* fln_g    = (const float*)d_in[20];
    const float* fln_b    = (const float*)d_in[21];
    const float* op_w     = (const float*)d_in[22];
    const float* op_b     = (const float*)d_in[23];
    float* out = (float*)d_out;

    char* ws = (char*)d_ws;
    float*  h     = (float*)(ws);                      //  8,192,000 B
    __bf16* qkvb  = (__bf16*)(ws + 8192000);           // 12,288,000 B
    __bf16* PA    = (__bf16*)(ws + 20480000);          //  4,096,000 B
    __bf16* PBq   = (__bf16*)(ws + 24576000);          //  1,572,864 B
    __bf16* PBo   = (__bf16*)(ws + 26148864);          //    524,288 B
    __bf16* PB1   = (__bf16*)(ws + 26673152);          //  2,097,152 B
    __bf16* PB2   = (__bf16*)(ws + 28770304);          //  2,097,152 B
    __bf16* PBp   = (__bf16*)(ws + 30867456);          //    262,144 B
    __bf16* PBop  = (__bf16*)(ws + 31129600);          //     65,536 B

    // ---- all weight packs, one kernel ----
    k_pack_all<<<1616, 256, 0, stream>>>(qkv_w, out_w, ff1_w, ff2_w, proj_w, op_w,
                                         PBq, PBo, PB1, PB2, PBp, PBop);

    // ---- patch fused (+ qkv for layer 0) ----
    k_patchfused<<<250, 256, 0, stream>>>(x, ln1_g, ln1_b, PBp, proj_b, h,
                                          ln2_g, ln2_b, ln_attn_g, ln_attn_b,
                                          PBq, qkv_b, qkvb);

    for (int l = 0; l < 4; l++) {
        dim3 ag(NB * NHEAD, 4);
        k_attn<<<ag, 512, 0, stream>>>(qkvb, rel_bias, PA);
        if (l < 3) {
            k_layer<0><<<250, 512, 0, stream>>>(PA, PBo + (size_t)l * 65536, out_b + l * 256,
                                                h, ln_ff_g + l * 256, ln_ff_b + l * 256,
                                                PB1 + (size_t)l * 262144, ff1_b + l * 1024,
                                                PB2 + (size_t)l * 262144, ff2_b + l * 256,
                                                ln_attn_g + (l + 1) * 256, ln_attn_b + (l + 1) * 256,
                                                PBq + (size_t)(l + 1) * 196608, qkv_b + (l + 1) * 768,
                                                qkvb, nullptr);
        } else {
            k_layer<1><<<250, 512, 0, stream>>>(PA, PBo + (size_t)l * 65536, out_b + l * 256,
                                                h, ln_ff_g + l * 256, ln_ff_b + l * 256,
                                                PB1 + (size_t)l * 262144, ff1_b + l * 1024,
                                                PB2 + (size_t)l * 262144, ff2_b + l * 256,
                                                fln_g, fln_b,
                                                PBop, op_b, nullptr, out);
        }
    }
}

// Round 18
// 282.989 us; speedup vs baseline: 1.1015x; 1.1015x over previous
//
#include <hip/hip_runtime.h>

#define TS 500      // n_patch (sequence length)
#define NB 16       // batch
#define NROW 8000   // NB * TS
#define DMODEL 256
#define NHEAD 8
#define HDIM 32
#define FFD 1024

typedef __bf16 bf16x8 __attribute__((ext_vector_type(8)));
typedef __bf16 bf16x4 __attribute__((ext_vector_type(4)));
typedef float  f32x4  __attribute__((ext_vector_type(4)));
typedef float  f32x2  __attribute__((ext_vector_type(2)));

__device__ __forceinline__ float wred_sum(float v) {
    #pragma unroll
    for (int off = 32; off; off >>= 1) v += __shfl_xor(v, off, 64);
    return v;
}

// A-fragment scatter store (global): element (grow, col) of [8000][K] bf16.
__device__ __forceinline__ void pa_store(__bf16* __restrict__ PA, int KS,
                                         int grow, int col, float y) {
    int mt = grow >> 4, rl = grow & 15;
    size_t idx = ((size_t)(mt * KS + (col >> 5)) * 64 + ((col >> 3) & 3) * 16 + rl) * 8 + (col & 7);
    PA[idx] = (__bf16)y;
}

// A-fragment scatter store (LDS, local row 0..15, KS=8)
__device__ __forceinline__ void ya_store(__bf16* __restrict__ YA,
                                         int lrow, int col, float y) {
    int mtl = lrow >> 4, rl = lrow & 15;
    int idx = (((mtl * 8 + (col >> 5)) * 64) + ((col >> 3) & 3) * 16 + rl) * 8 + (col & 7);
    YA[idx] = (__bf16)y;
}

// ---------------------------------------------------------------------------
// All weight packs in ONE kernel (unchanged, passing).
// ---------------------------------------------------------------------------
__global__ __launch_bounds__(256) void k_pack_all(
    const float* __restrict__ qkv_w, const float* __restrict__ out_w,
    const float* __restrict__ ff1_w, const float* __restrict__ ff2_w,
    const float* __restrict__ proj_w, const float* __restrict__ op_w,
    __bf16* __restrict__ PBq, __bf16* __restrict__ PBo,
    __bf16* __restrict__ PB1, __bf16* __restrict__ PB2,
    __bf16* __restrict__ PBp, __bf16* __restrict__ PBop)
{
    int bid = blockIdx.x;
    const float* W; __bf16* PB; int KS, NT, wLS, pLS, l, bx;
    if (bid < 384)       { W = qkv_w;  PB = PBq;  KS = 8;  NT = 48; wLS = 196608; pLS = 196608; l = bid / 96;           bx = bid % 96; }
    else if (bid < 512)  { W = out_w;  PB = PBo;  KS = 8;  NT = 16; wLS = 65536;  pLS = 65536;  l = (bid - 384) / 32;   bx = (bid - 384) % 32; }
    else if (bid < 1024) { W = ff1_w;  PB = PB1;  KS = 8;  NT = 64; wLS = 262144; pLS = 262144; l = (bid - 512) / 128;  bx = (bid - 512) % 128; }
    else if (bid < 1536) { W = ff2_w;  PB = PB2;  KS = 32; NT = 16; wLS = 262144; pLS = 262144; l = (bid - 1024) / 128; bx = (bid - 1024) % 128; }
    else if (bid < 1600) { W = proj_w; PB = PBp;  KS = 16; NT = 16; wLS = 0;      pLS = 0;      l = 0;                  bx = bid - 1536; }
    else                 { W = op_w;   PB = PBop; KS = 8;  NT = 8;  wLS = 0;      pLS = 0;      l = 0;                  bx = bid - 1600; }

    int gid = bx * 256 + threadIdx.x;
    if (gid >= NT * KS * 64) return;
    int lane = gid & 63;
    int ks = (gid >> 6) % KS;
    int nt = (gid >> 6) / KS;
    int N = NT * 16;
    int k0 = ks * 32 + (lane >> 4) * 8;
    int col = nt * 16 + (lane & 15);
    const float* src = W + (size_t)l * wLS;
    bf16x8 v;
    #pragma unroll
    for (int j = 0; j < 8; j++) v[j] = (__bf16)src[(size_t)(k0 + j) * N + col];
    *(bf16x8*)(PB + (size_t)l * pLS + ((size_t)(nt * KS + ks) * 64 + lane) * 8) = v;
}

// ---------------------------------------------------------------------------
// Patch stage FUSED + qkv[0] (unchanged, passing).
// ---------------------------------------------------------------------------
__global__ __launch_bounds__(256) void k_patchfused(
    const float* __restrict__ x, const float* __restrict__ g1, const float* __restrict__ b1,
    const __bf16* __restrict__ PBp, const float* __restrict__ bias,
    float* __restrict__ h,
    const float* __restrict__ gam, const float* __restrict__ bet,
    const float* __restrict__ gam2, const float* __restrict__ bet2,
    const __bf16* __restrict__ PBq0, const float* __restrict__ qb0,
    __bf16* __restrict__ qkvb)
{
    __shared__ __align__(16) __bf16 As[2][16][64][8];
    __shared__ float redS[4][32];
    __shared__ float redQ[4][32];
    int t = threadIdx.x, lane = t & 63, w = t >> 6;
    int row0 = blockIdx.x * 32;

    for (int rr = 0; rr < 8; rr++) {
        int lrow = w * 8 + rr;
        int row = row0 + lrow;
        int b = row / TS, pp = row - b * TS;
        int kb = lane * 8;
        const float* src = x + ((size_t)(pp * 4 + (kb >> 7)) * NB + b) * 128 + (kb & 127);
        float4 lo = *(const float4*)src;
        float4 hi = *(const float4*)(src + 4);
        float v[8] = {lo.x, lo.y, lo.z, lo.w, hi.x, hi.y, hi.z, hi.w};
        float sm_ = 0.f;
        #pragma unroll
        for (int j = 0; j < 8; j++) sm_ += v[j];
        sm_ = wred_sum(sm_);
        float mu = sm_ * (1.0f / 512.0f);
        float q = 0.f;
        #pragma unroll
        for (int j = 0; j < 8; j++) { float d = v[j] - mu; q += d * d; }
        q = wred_sum(q);
        float rs = rsqrtf(q * (1.0f / 512.0f) + 1e-6f);
        float4 gl = *(const float4*)(g1 + kb), gh = *(const float4*)(g1 + kb + 4);
        float4 bl = *(const float4*)(b1 + kb), bh = *(const float4*)(b1 + kb + 4);
        float gg[8] = {gl.x, gl.y, gl.z, gl.w, gh.x, gh.y, gh.z, gh.w};
        float bbv[8] = {bl.x, bl.y, bl.z, bl.w, bh.x, bh.y, bh.z, bh.w};
        bf16x8 yv;
        #pragma unroll
        for (int j = 0; j < 8; j++) yv[j] = (__bf16)((v[j] - mu) * rs * gg[j] + bbv[j]);
        *(bf16x8*)&As[lrow >> 4][lane >> 2][(lane & 3) * 16 + (lrow & 15)][0] = yv;
    }
    __syncthreads();

    const bf16x8* B8 = (const bf16x8*)PBp;
    f32x4 acc[2][4] = {};
    #pragma unroll 8
    for (int ks = 0; ks < 16; ks++) {
        bf16x8 a0 = *(const bf16x8*)&As[0][ks][lane][0];
        bf16x8 a1 = *(const bf16x8*)&As[1][ks][lane][0];
        #pragma unroll
        for (int n = 0; n < 4; n++) {
            bf16x8 b = B8[((size_t)(w * 4 + n) * 16 + ks) * 64 + lane];
            acc[0][n] = __builtin_amdgcn_mfma_f32_16x16x32_bf16(a0, b, acc[0][n], 0, 0, 0);
            acc[1][n] = __builtin_amdgcn_mfma_f32_16x16x32_bf16(a1, b, acc[1][n], 0, 0, 0);
        }
    }

    int g_ = lane >> 4, cl = lane & 15;
    int rbase = g_ * 4;
    float gamv[4], betv[4], gam2v[4], bet2v[4];
    #pragma unroll
    for (int n = 0; n < 4; n++) {
        int col = (w * 4 + n) * 16 + cl;
        float bv = bias[col];
        gamv[n] = gam[col]; betv[n] = bet[col];
        gam2v[n] = gam2[col]; bet2v[n] = bet2[col];
        #pragma unroll
        for (int m = 0; m < 2; m++)
            #pragma unroll
            for (int r = 0; r < 4; r++) acc[m][n][r] += bv;
    }
    float mu[2][4], rstd[2][4];
    {
        float ps[2][4];
        #pragma unroll
        for (int m = 0; m < 2; m++)
            #pragma unroll
            for (int r = 0; r < 4; r++) {
                float s2 = acc[m][0][r] + acc[m][1][r] + acc[m][2][r] + acc[m][3][r];
                #pragma unroll
                for (int off = 1; off < 16; off <<= 1) s2 += __shfl_xor(s2, off, 64);
                ps[m][r] = s2;
            }
        if (cl == 0)
            #pragma unroll
            for (int m = 0; m < 2; m++)
                #pragma unroll
                for (int r = 0; r < 4; r++) redS[w][m * 16 + rbase + r] = ps[m][r];
        __syncthreads();
        #pragma unroll
        for (int m = 0; m < 2; m++)
            #pragma unroll
            for (int r = 0; r < 4; r++) {
                int lr = m * 16 + rbase + r;
                mu[m][r] = (redS[0][lr] + redS[1][lr] + redS[2][lr] + redS[3][lr]) * (1.0f / 256.0f);
            }
        float pq[2][4];
        #pragma unroll
        for (int m = 0; m < 2; m++)
            #pragma unroll
            for (int r = 0; r < 4; r++) {
                float s2 = 0.f;
                #pragma unroll
                for (int n = 0; n < 4; n++) { float d = acc[m][n][r] - mu[m][r]; s2 += d * d; }
                #pragma unroll
                for (int off = 1; off < 16; off <<= 1) s2 += __shfl_xor(s2, off, 64);
                pq[m][r] = s2;
            }
        if (cl == 0)
            #pragma unroll
            for (int m = 0; m < 2; m++)
                #pragma unroll
                for (int r = 0; r < 4; r++) redQ[w][m * 16 + rbase + r] = pq[m][r];
        __syncthreads();
        #pragma unroll
        for (int m = 0; m < 2; m++)
            #pragma unroll
            for (int r = 0; r < 4; r++) {
                int lr = m * 16 + rbase + r;
                float var = (redQ[0][lr] + redQ[1][lr] + redQ[2][lr] + redQ[3][lr]) * (1.0f / 256.0f);
                rstd[m][r] = rsqrtf(var + 1e-6f);
            }
    }
    float ps2[2][4];
    #pragma unroll
    for (int m = 0; m < 2; m++) {
        int row = row0 + m * 16 + rbase;
        #pragma unroll
        for (int r = 0; r < 4; r++) {
            float s2 = 0.f;
            #pragma unroll
            for (int n = 0; n < 4; n++) {
                int col = (w * 4 + n) * 16 + cl;
                float y1 = (acc[m][n][r] - mu[m][r]) * rstd[m][r] * gamv[n] + betv[n];
                h[(size_t)(row + r) * 256 + col] = y1;
                s2 += y1;
            }
            #pragma unroll
            for (int off = 1; off < 16; off <<= 1) s2 += __shfl_xor(s2, off, 64);
            ps2[m][r] = s2;
        }
    }
    if (cl == 0)
        #pragma unroll
        for (int m = 0; m < 2; m++)
            #pragma unroll
            for (int r = 0; r < 4; r++) redS[w][m * 16 + rbase + r] = ps2[m][r];
    __syncthreads();
    float mu2[2][4], rstd2[2][4];
    #pragma unroll
    for (int m = 0; m < 2; m++)
        #pragma unroll
        for (int r = 0; r < 4; r++) {
            int lr = m * 16 + rbase + r;
            mu2[m][r] = (redS[0][lr] + redS[1][lr] + redS[2][lr] + redS[3][lr]) * (1.0f / 256.0f);
        }
    float pq2[2][4];
    #pragma unroll
    for (int m = 0; m < 2; m++)
        #pragma unroll
        for (int r = 0; r < 4; r++) {
            float s2 = 0.f;
            #pragma unroll
            for (int n = 0; n < 4; n++) {
                float y1 = (acc[m][n][r] - mu[m][r]) * rstd[m][r] * gamv[n] + betv[n];
                float d = y1 - mu2[m][r];
                s2 += d * d;
            }
            #pragma unroll
            for (int off = 1; off < 16; off <<= 1) s2 += __shfl_xor(s2, off, 64);
            pq2[m][r] = s2;
        }
    if (cl == 0)
        #pragma unroll
        for (int m = 0; m < 2; m++)
            #pragma unroll
            for (int r = 0; r < 4; r++) redQ[w][m * 16 + rbase + r] = pq2[m][r];
    __syncthreads();
    #pragma unroll
    for (int m = 0; m < 2; m++)
        #pragma unroll
        for (int r = 0; r < 4; r++) {
            int lr = m * 16 + rbase + r;
            float var = (redQ[0][lr] + redQ[1][lr] + redQ[2][lr] + redQ[3][lr]) * (1.0f / 256.0f);
            rstd2[m][r] = rsqrtf(var + 1e-5f);
        }
    __bf16* YA = &As[0][0][0][0];
    #pragma unroll
    for (int m = 0; m < 2; m++) {
        #pragma unroll
        for (int n = 0; n < 4; n++) {
            int col = (w * 4 + n) * 16 + cl;
            #pragma unroll
            for (int r = 0; r < 4; r++) {
                float y1 = (acc[m][n][r] - mu[m][r]) * rstd[m][r] * gamv[n] + betv[n];
                float y2 = (y1 - mu2[m][r]) * rstd2[m][r] * gam2v[n] + bet2v[n];
                ya_store(YA, m * 16 + rbase + r, col, y2);
            }
        }
    }
    __syncthreads();

    const bf16x8* YA8 = (const bf16x8*)YA;
    const bf16x8* B8q = (const bf16x8*)PBq0;
    for (int m = 0; m < 2; m++) {
        f32x4 acc2[12] = {};
        for (int ks = 0; ks < 8; ks++) {
            bf16x8 a = YA8[(m * 8 + ks) * 64 + lane];
            #pragma unroll
            for (int n = 0; n < 12; n++) {
                bf16x8 b = B8q[((size_t)(w * 12 + n) * 8 + ks) * 64 + lane];
                acc2[n] = __builtin_amdgcn_mfma_f32_16x16x32_bf16(a, b, acc2[n], 0, 0, 0);
            }
        }
        int row = row0 + m * 16 + rbase;
        #pragma unroll
        for (int n = 0; n < 12; n++) {
            int col = (w * 12 + n) * 16 + cl;
            float bv = qb0[col];
            #pragma unroll
            for (int r = 0; r < 4; r++)
                qkvb[(size_t)(row + r) * 768 + col] = (__bf16)(acc2[n][r] + bv);
        }
    }
}

// ---------------------------------------------------------------------------
// FULL LAYER TAIL: out-proj + residual (h in regs) + LN_ff -> YA(LDS) ->
// ff1 + GELU -> F1T -> ff2 + residual -> h (single write) + LN -> YA ->
// tail GEMM (MODE 0: qkv[l+1]; MODE 1: final projection, swapaxes).
// 512 threads / 8 waves, 16 rows/block, grid 500. LDS ~41 KB.
// ---------------------------------------------------------------------------
template<int MODE>
__global__ __launch_bounds__(512) void k_layer(
    const __bf16* __restrict__ PAattn, const __bf16* __restrict__ PBo,
    const float* __restrict__ ob, float* __restrict__ h,
    const float* __restrict__ fg, const float* __restrict__ fb,
    const __bf16* __restrict__ PB1, const float* __restrict__ b1,
    const __bf16* __restrict__ PB2, const float* __restrict__ b2,
    const float* __restrict__ gam, const float* __restrict__ bet,
    const __bf16* __restrict__ PBn, const float* __restrict__ bn,
    __bf16* __restrict__ qkvb, float* __restrict__ outp)
{
    __shared__ __align__(16) __bf16 YA[8 * 64 * 8];  // 8 KB A-frags (16 rows)
    __shared__ __align__(16) __bf16 F1T[1024][16];   // 32 KB
    __shared__ float redS[8][16];
    __shared__ float redQ[8][16];
    int t = threadIdx.x, lane = t & 63, w = t >> 6;  // w in 0..7
    int mt = blockIdx.x;
    int g_ = lane >> 4, cl = lane & 15, rbase = g_ * 4;
    int row = mt * 16 + rbase;

    const bf16x8* A8 = (const bf16x8*)PAattn;
    const bf16x8* B8o = (const bf16x8*)PBo;
    const bf16x8* B81 = (const bf16x8*)PB1;
    const bf16x8* B82 = (const bf16x8*)PB2;

    // ---- Phase 0: out-projection GEMM (K=256), wave owns 2 n-tiles ----
    f32x4 hv[2] = {};
    {
        f32x4 acc0[2] = {};
        #pragma unroll 8
        for (int ks = 0; ks < 8; ks++) {
            bf16x8 a = A8[((size_t)mt * 8 + ks) * 64 + lane];
            #pragma unroll
            for (int n = 0; n < 2; n++) {
                bf16x8 b = B8o[((size_t)(w * 2 + n) * 8 + ks) * 64 + lane];
                acc0[n] = __builtin_amdgcn_mfma_f32_16x16x32_bf16(a, b, acc0[n], 0, 0, 0);
            }
        }
        #pragma unroll
        for (int n = 0; n < 2; n++) {
            int col = (w * 2 + n) * 16 + cl;
            float bv = ob[col];
            #pragma unroll
            for (int r = 0; r < 4; r++)
                hv[n][r] = acc0[n][r] + bv + h[(size_t)(row + r) * 256 + col];
        }
    }
    // ---- LN_ff(hv) -> YA ----
    {
        float mu[4], rstd[4];
        float ps[4];
        #pragma unroll
        for (int r = 0; r < 4; r++) {
            float s2 = hv[0][r] + hv[1][r];
            #pragma unroll
            for (int off = 1; off < 16; off <<= 1) s2 += __shfl_xor(s2, off, 64);
            ps[r] = s2;
        }
        if (cl == 0)
            #pragma unroll
            for (int r = 0; r < 4; r++) redS[w][rbase + r] = ps[r];
        __syncthreads();
        #pragma unroll
        for (int r = 0; r < 4; r++) {
            int lr = rbase + r;
            float s2 = 0.f;
            #pragma unroll
            for (int ww = 0; ww < 8; ww++) s2 += redS[ww][lr];
            mu[r] = s2 * (1.0f / 256.0f);
        }
        float pq[4];
        #pragma unroll
        for (int r = 0; r < 4; r++) {
            float s2 = 0.f;
            #pragma unroll
            for (int n = 0; n < 2; n++) { float d = hv[n][r] - mu[r]; s2 += d * d; }
            #pragma unroll
            for (int off = 1; off < 16; off <<= 1) s2 += __shfl_xor(s2, off, 64);
            pq[r] = s2;
        }
        if (cl == 0)
            #pragma unroll
            for (int r = 0; r < 4; r++) redQ[w][rbase + r] = pq[r];
        __syncthreads();
        #pragma unroll
        for (int r = 0; r < 4; r++) {
            int lr = rbase + r;
            float s2 = 0.f;
            #pragma unroll
            for (int ww = 0; ww < 8; ww++) s2 += redQ[ww][lr];
            rstd[r] = rsqrtf(s2 * (1.0f / 256.0f) + 1e-5f);
        }
        #pragma unroll
        for (int n = 0; n < 2; n++) {
            int col = (w * 2 + n) * 16 + cl;
            float gv = fg[col], bv = fb[col];
            #pragma unroll
            for (int r = 0; r < 4; r++) {
                float y = (hv[n][r] - mu[r]) * rstd[r] * gv + bv;
                ya_store(YA, rbase + r, col, y);
            }
        }
    }
    __syncthreads();

    // ---- Phase A: ff1 from YA, wave owns 8 n-tiles (128 cols) ----
    const bf16x8* YA8 = (const bf16x8*)YA;
    {
        f32x4 acc1[8] = {};
        #pragma unroll 2
        for (int ks = 0; ks < 8; ks++) {
            bf16x8 a = YA8[ks * 64 + lane];
            #pragma unroll
            for (int n = 0; n < 8; n++) {
                bf16x8 b = B81[((size_t)(w * 8 + n) * 8 + ks) * 64 + lane];
                acc1[n] = __builtin_amdgcn_mfma_f32_16x16x32_bf16(a, b, acc1[n], 0, 0, 0);
            }
        }
        #pragma unroll
        for (int n = 0; n < 8; n++) {
            int col = (w * 8 + n) * 16 + cl;
            float bv = b1[col];
            bf16x4 pv;
            #pragma unroll
            for (int r = 0; r < 4; r++) {
                float xx = acc1[n][r] + bv;
                pv[r] = (__bf16)(0.5f * xx * (1.0f + erff(xx * 0.70710678118654752f)));
            }
            *(bf16x4*)&F1T[col][rbase] = pv;
        }
    }
    __syncthreads();

    // ---- Phase B: ff2 via tr_b16, wave owns 2 n-tiles ----
    f32x4 acc[2] = {};
    for (int kb = 0; kb < 8; kb++) {
        f32x2 lo[4], hi[4];
        #pragma unroll
        for (int q = 0; q < 4; q++) {
            unsigned ta = (unsigned)(uintptr_t)&F1T[(kb * 4 + q) * 32 + 8 * g_][0] + cl * 8;
            asm volatile("ds_read_b64_tr_b16 %0, %1" : "=v"(lo[q]) : "v"(ta) : "memory");
            asm volatile("ds_read_b64_tr_b16 %0, %1 offset:128" : "=v"(hi[q]) : "v"(ta) : "memory");
        }
        asm volatile("s_waitcnt lgkmcnt(0)" ::: "memory");
        __builtin_amdgcn_sched_barrier(0);
        #pragma unroll
        for (int q = 0; q < 4; q++) {
            int ks = kb * 4 + q;
            f32x4 pc = {lo[q][0], lo[q][1], hi[q][0], hi[q][1]};
            bf16x8 a = __builtin_bit_cast(bf16x8, pc);
            #pragma unroll
            for (int n = 0; n < 2; n++) {
                bf16x8 b = B82[((size_t)(w * 2 + n) * 32 + ks) * 64 + lane];
                acc[n] = __builtin_amdgcn_mfma_f32_16x16x32_bf16(a, b, acc[n], 0, 0, 0);
            }
        }
    }

    // ---- EPI: +b2, residual (hv), single h write, LN -> YA ----
    float gamv[2], betv[2];
    #pragma unroll
    for (int n = 0; n < 2; n++) {
        int col = (w * 2 + n) * 16 + cl;
        float bv = b2[col];
        gamv[n] = gam[col]; betv[n] = bet[col];
        #pragma unroll
        for (int r = 0; r < 4; r++) {
            float v = acc[n][r] + bv + hv[n][r];
            h[(size_t)(row + r) * 256 + col] = v;
            acc[n][r] = v;
        }
    }
    {
        float mu[4], rstd[4];
        float ps[4];
        #pragma unroll
        for (int r = 0; r < 4; r++) {
            float s2 = acc[0][r] + acc[1][r];
            #pragma unroll
            for (int off = 1; off < 16; off <<= 1) s2 += __shfl_xor(s2, off, 64);
            ps[r] = s2;
        }
        if (cl == 0)
            #pragma unroll
            for (int r = 0; r < 4; r++) redS[w][rbase + r] = ps[r];
        __syncthreads();
        #pragma unroll
        for (int r = 0; r < 4; r++) {
            int lr = rbase + r;
            float s2 = 0.f;
            #pragma unroll
            for (int ww = 0; ww < 8; ww++) s2 += redS[ww][lr];
            mu[r] = s2 * (1.0f / 256.0f);
        }
        float pq[4];
        #pragma unroll
        for (int r = 0; r < 4; r++) {
            float s2 = 0.f;
            #pragma unroll
            for (int n = 0; n < 2; n++) { float d = acc[n][r] - mu[r]; s2 += d * d; }
            #pragma unroll
            for (int off = 1; off < 16; off <<= 1) s2 += __shfl_xor(s2, off, 64);
            pq[r] = s2;
        }
        if (cl == 0)
            #pragma unroll
            for (int r = 0; r < 4; r++) redQ[w][rbase + r] = pq[r];
        __syncthreads();
        #pragma unroll
        for (int r = 0; r < 4; r++) {
            int lr = rbase + r;
            float s2 = 0.f;
            #pragma unroll
            for (int ww = 0; ww < 8; ww++) s2 += redQ[ww][lr];
            rstd[r] = rsqrtf(s2 * (1.0f / 256.0f) + 1e-5f);
        }
        #pragma unroll
        for (int n = 0; n < 2; n++) {
            int col = (w * 2 + n) * 16 + cl;
            #pragma unroll
            for (int r = 0; r < 4; r++) {
                float y = (acc[n][r] - mu[r]) * rstd[r] * gamv[n] + betv[n];
                ya_store(YA, rbase + r, col, y);
            }
        }
    }
    __syncthreads();

    // ---- tail GEMM from YA ----
    const bf16x8* B8n = (const bf16x8*)PBn;
    if constexpr (MODE == 0) {
        f32x4 acc2[6] = {};
        for (int ks = 0; ks < 8; ks++) {
            bf16x8 a = YA8[ks * 64 + lane];
            #pragma unroll
            for (int n = 0; n < 6; n++) {
                bf16x8 b = B8n[((size_t)(w * 6 + n) * 8 + ks) * 64 + lane];
                acc2[n] = __builtin_amdgcn_mfma_f32_16x16x32_bf16(a, b, acc2[n], 0, 0, 0);
            }
        }
        #pragma unroll
        for (int n = 0; n < 6; n++) {
            int col = (w * 6 + n) * 16 + cl;
            float bv = bn[col];
            #pragma unroll
            for (int r = 0; r < 4; r++)
                qkvb[(size_t)(row + r) * 768 + col] = (__bf16)(acc2[n][r] + bv);
        }
    } else {
        f32x4 acc2 = {};
        #pragma unroll 4
        for (int ks = 0; ks < 8; ks++) {
            bf16x8 a = YA8[ks * 64 + lane];
            bf16x8 b = B8n[((size_t)w * 8 + ks) * 64 + lane];
            acc2 = __builtin_amdgcn_mfma_f32_16x16x32_bf16(a, b, acc2, 0, 0, 0);
        }
        int col = w * 16 + cl;
        float bv = bn[col];
        #pragma unroll
        for (int r = 0; r < 4; r++) {
            int grow = row + r;
            int bq = grow / TS, pp = grow - bq * TS;
            outp[((size_t)pp * NB + bq) * 128 + col] = acc2[r] + bv;
        }
    }
}

// ---------------------------------------------------------------------------
// MFMA flash attention, qt-PAIRED (unchanged, passing).
// ---------------------------------------------------------------------------
__global__ __launch_bounds__(512) void k_attn(
    const __bf16* __restrict__ qkv, const float* __restrict__ rel_bias,
    __bf16* __restrict__ PA)
{
    __shared__ __align__(16) __bf16 Kfr[4][64][8];
    __shared__ __align__(16) __bf16 Vpl[2][64][16];
    __shared__ __align__(16) __bf16 PT[8][64][16];
    __shared__ float bias_s[132];

    int bh = blockIdx.x;
    int pr = 3 - blockIdx.y;
    int b = bh >> 3, hh = bh & 7;
    int t = threadIdx.x, lane = t & 63, w = t >> 6;
    int wg = w & 3, grp = w >> 2;
    int qt = 2 * pr + 1 - grp;
    int q0 = qt * 64 + wg * 16;
    int c = lane & 15, g = lane >> 4;

    const __bf16* base = qkv + (size_t)b * TS * 768 + hh * 32;

    if (t < 129) bias_s[t] = rel_bias[hh * 129 + t];

    bf16x8 aq = {};
    {
        int qi = q0 + c;
        if (qi < TS) aq = *(const bf16x8*)(base + (size_t)qi * 768 + 8 * g);
    }

    float lpart[4] = {0.f, 0.f, 0.f, 0.f};
    f32x4 O0 = {}, O1 = {};
    const float scale = 0.17677669529663687f;

    int nj = 2 * pr + 2;

    for (int it = 0; it < nj; it++) {
        int j0 = it * 64;
        __syncthreads();
        if (w < 4) {
            int j = j0 + w * 16 + c;
            bf16x8 kv = {};
            if (j < TS) kv = *(const bf16x8*)(base + (size_t)j * 768 + 256 + 8 * g);
            *(bf16x8*)&Kfr[w][lane][0] = kv;
        } else {
            int t2 = t - 256;
            int jl = t2 >> 2, dseg = t2 & 3;
            int j = j0 + jl;
            bf16x8 vv = {};
            if (j < TS) vv = *(const bf16x8*)(base + (size_t)j * 768 + 512 + 8 * dseg);
            *(bf16x8*)&Vpl[dseg >> 1][jl][(dseg & 1) * 8] = vv;
        }
        __syncthreads();

        if (it > qt) continue;

        f32x4 S[4];
        f32x4 zero = {};
        #pragma unroll
        for (int jt = 0; jt < 4; jt++) {
            bf16x8 bk = *(const bf16x8*)&Kfr[jt][lane][0];
            S[jt] = __builtin_amdgcn_mfma_f32_16x16x32_bf16(aq, bk, zero, 0, 0, 0);
        }

        #pragma unroll
        for (int jt = 0; jt < 4; jt++) {
            int j = j0 + jt * 16 + c;
            #pragma unroll
            for (int r = 0; r < 4; r++) {
                int i = q0 + 4 * g + r;
                int rel = j - i;
                rel = rel < -64 ? -64 : (rel > 64 ? 64 : rel);
                float sv = S[jt][r] * scale + bias_s[rel + 64];
                float pr_ = (j > i) ? 0.f : __expf(sv);
                S[jt][r] = pr_;
                lpart[r] += pr_;
            }
        }

        #pragma unroll
        for (int jt = 0; jt < 4; jt++) {
            bf16x4 pv;
            pv[0] = (__bf16)S[jt][0]; pv[1] = (__bf16)S[jt][1];
            pv[2] = (__bf16)S[jt][2]; pv[3] = (__bf16)S[jt][3];
            *(bf16x4*)&PT[w][jt * 16 + c][4 * g] = pv;
        }
        asm volatile("s_waitcnt lgkmcnt(0)" ::: "memory");
        __builtin_amdgcn_sched_barrier(0);

        f32x2 pa_lo[2], pa_hi[2], vb_lo[2][2], vb_hi[2][2];
        #pragma unroll
        for (int jb = 0; jb < 2; jb++) {
            unsigned pta = (unsigned)(uintptr_t)&PT[w][jb * 32 + 8 * g][0] + c * 8;
            asm volatile("ds_read_b64_tr_b16 %0, %1" : "=v"(pa_lo[jb]) : "v"(pta) : "memory");
            asm volatile("ds_read_b64_tr_b16 %0, %1 offset:128" : "=v"(pa_hi[jb]) : "v"(pta) : "memory");
            #pragma unroll
            for (int dh = 0; dh < 2; dh++) {
                unsigned vta = (unsigned)(uintptr_t)&Vpl[dh][jb * 32 + 8 * g][0] + c * 8;
                asm volatile("ds_read_b64_tr_b16 %0, %1" : "=v"(vb_lo[jb][dh]) : "v"(vta) : "memory");
                asm volatile("ds_read_b64_tr_b16 %0, %1 offset:128" : "=v"(vb_hi[jb][dh]) : "v"(vta) : "memory");
            }
        }
        asm volatile("s_waitcnt lgkmcnt(0)" ::: "memory");
        __builtin_amdgcn_sched_barrier(0);

        #pragma unroll
        for (int jb = 0; jb < 2; jb++) {
            f32x4 pc = {pa_lo[jb][0], pa_lo[jb][1], pa_hi[jb][0], pa_hi[jb][1]};
            bf16x8 pa = __builtin_bit_cast(bf16x8, pc);
            f32x4 v0c = {vb_lo[jb][0][0], vb_lo[jb][0][1], vb_hi[jb][0][0], vb_hi[jb][0][1]};
            f32x4 v1c = {vb_lo[jb][1][0], vb_lo[jb][1][1], vb_hi[jb][1][0], vb_hi[jb][1][1]};
            bf16x8 vb0 = __builtin_bit_cast(bf16x8, v0c);
            bf16x8 vb1 = __builtin_bit_cast(bf16x8, v1c);
            O0 = __builtin_amdgcn_mfma_f32_16x16x32_bf16(pa, vb0, O0, 0, 0, 0);
            O1 = __builtin_amdgcn_mfma_f32_16x16x32_bf16(pa, vb1, O1, 0, 0, 0);
        }
    }

    #pragma unroll
    for (int r = 0; r < 4; r++) {
        #pragma unroll
        for (int off = 1; off < 16; off <<= 1) lpart[r] += __shfl_xor(lpart[r], off, 64);
    }
    #pragma unroll
    for (int r = 0; r < 4; r++) {
        int i = q0 + 4 * g + r;
        if (i < TS) {
            float inv = 1.0f / lpart[r];
            int grow = b * TS + i;
            int mt = grow >> 4, rl = grow & 15;
            size_t fb = (size_t)(mt * 8 + hh) * 64;
            PA[(fb + ((c >> 3) & 1) * 16 + rl) * 8 + (c & 7)]       = (__bf16)(O0[r] * inv);
            PA[(fb + (2 + ((c >> 3) & 1)) * 16 + rl) * 8 + (c & 7)] = (__bf16)(O1[r] * inv);
        }
    }
}

extern "C" void kernel_launch(void* const* d_in, const int* in_sizes, int n_in,
                              void* d_out, int out_size, void* d_ws, size_t ws_size,
                              hipStream_t stream)
{
    const float* x        = (const float*)d_in[0];
    const float* ln1_g    = (const float*)d_in[1];
    const float* ln1_b    = (const float*)d_in[2];
    const float* proj_w   = (const float*)d_in[3];
    const float* proj_b   = (const float*)d_in[4];
    const float* ln2_g    = (const float*)d_in[5];
    const float* ln2_b    = (const float*)d_in[6];
    const float* rel_bias = (const float*)d_in[7];
    const float* ln_attn_g= (const float*)d_in[8];
    const float* ln_attn_b= (const float*)d_in[9];
    const float* qkv_w    = (const float*)d_in[10];
    const float* qkv_b    = (const float*)d_in[11];
    const float* out_w    = (const float*)d_in[12];
    const float* out_b    = (const float*)d_in[13];
    const float* ln_ff_g  = (const float*)d_in[14];
    const float* ln_ff_b  = (const float*)d_in[15];
    const float* ff1_w    = (const float*)d_in[16];
    const float* ff1_b    = (const float*)d_in[17];
    const float* ff2_w    = (const float*)d_in[18];
    const float* ff2_b    = (const float*)d_in[19];
    const float* fln_g    = (const float*)d_in[20];
    const float* fln_b    = (const float*)d_in[21];
    const float* op_w     = (const float*)d_in[22];
    const float* op_b     = (const float*)d_in[23];
    float* out = (float*)d_out;

    char* ws = (char*)d_ws;
    float*  h     = (float*)(ws);                      //  8,192,000 B
    __bf16* qkvb  = (__bf16*)(ws + 8192000);           // 12,288,000 B
    __bf16* PA    = (__bf16*)(ws + 20480000);          //  4,096,000 B
    __bf16* PBq   = (__bf16*)(ws + 24576000);          //  1,572,864 B
    __bf16* PBo   = (__bf16*)(ws + 26148864);          //    524,288 B
    __bf16* PB1   = (__bf16*)(ws + 26673152);          //  2,097,152 B
    __bf16* PB2   = (__bf16*)(ws + 28770304);          //  2,097,152 B
    __bf16* PBp   = (__bf16*)(ws + 30867456);          //    262,144 B
    __bf16* PBop  = (__bf16*)(ws + 31129600);          //     65,536 B

    // ---- all weight packs, one kernel ----
    k_pack_all<<<1616, 256, 0, stream>>>(qkv_w, out_w, ff1_w, ff2_w, proj_w, op_w,
                                         PBq, PBo, PB1, PB2, PBp, PBop);

    // ---- patch fused (+ qkv for layer 0) ----
    k_patchfused<<<250, 256, 0, stream>>>(x, ln1_g, ln1_b, PBp, proj_b, h,
                                          ln2_g, ln2_b, ln_attn_g, ln_attn_b,
                                          PBq, qkv_b, qkvb);

    for (int l = 0; l < 4; l++) {
        dim3 ag(NB * NHEAD, 4);
        k_attn<<<ag, 512, 0, stream>>>(qkvb, rel_bias, PA);
        if (l < 3) {
            k_layer<0><<<500, 512, 0, stream>>>(PA, PBo + (size_t)l * 65536, out_b + l * 256,
                                                h, ln_ff_g + l * 256, ln_ff_b + l * 256,
                                                PB1 + (size_t)l * 262144, ff1_b + l * 1024,
                                                PB2 + (size_t)l * 262144, ff2_b + l * 256,
                                                ln_attn_g + (l + 1) * 256, ln_attn_b + (l + 1) * 256,
                                                PBq + (size_t)(l + 1) * 196608, qkv_b + (l + 1) * 768,
                                                qkvb, nullptr);
        } else {
            k_layer<1><<<500, 512, 0, stream>>>(PA, PBo + (size_t)l * 65536, out_b + l * 256,
                                                h, ln_ff_g + l * 256, ln_ff_b + l * 256,
                                                PB1 + (size_t)l * 262144, ff1_b + l * 1024,
                                                PB2 + (size_t)l * 262144, ff2_b + l * 256,
                                                fln_g, fln_b,
                                                PBop, op_b, nullptr, out);
        }
    }
}